// Round 1
// baseline (950.826 us; speedup 1.0000x reference)
//
#include <hip/hip_runtime.h>
#include <hip/hip_bf16.h>

#define NN 100000     // nodes
#define FIN 128
#define EMB 64

// ---------------------------------------------------------------- degree ----
__global__ void deg_init_k(float* __restrict__ deg) {
    int i = blockIdx.x * blockDim.x + threadIdx.x;
    if (i < NN) deg[i] = 1.0f;   // self-loop
}

__global__ void deg_count_k(const int* __restrict__ dst, float* __restrict__ deg, int n_edges) {
    int e = blockIdx.x * blockDim.x + threadIdx.x;
    if (e < n_edges) atomicAdd(&deg[dst[e]], 1.0f);
}

__global__ void dinv_k(float* __restrict__ deg) {
    int i = blockIdx.x * blockDim.x + threadIdx.x;
    if (i < NN) deg[i] = rsqrtf(deg[i]);   // deg >= 1 always
}

// ---------------------------------------------------------------- GEMM ------
// Y[N,64] = X[N,K] @ W[K,64].  Block = 256 threads = 4 rows x 64 outputs.
// W staged in LDS once per block; grid-stride over row-chunks of 4.
template <int K>
__global__ void gemm_rows_k(const float* __restrict__ X, const float* __restrict__ W,
                            float* __restrict__ Y, int n_rows) {
    __shared__ float Wl[K * 64];
    __shared__ float Xl[4][K];
    for (int i = threadIdx.x; i < K * 64; i += blockDim.x) Wl[i] = W[i];

    const int o    = threadIdx.x & 63;   // output feature
    const int rloc = threadIdx.x >> 6;   // row within chunk (0..3)

    for (int base = blockIdx.x * 4; base < n_rows; base += gridDim.x * 4) {
        __syncthreads();                 // protect Xl (and first-iter W) reuse
        for (int i = threadIdx.x; i < 4 * K; i += blockDim.x) {
            int r = i / K, k = i - r * K;
            int row = base + r;
            Xl[r][k] = (row < n_rows) ? X[row * K + k] : 0.0f;
        }
        __syncthreads();
        int row = base + rloc;
        if (row < n_rows) {
            float acc = 0.0f;
#pragma unroll
            for (int k = 0; k < K; ++k)
                acc = fmaf(Xl[rloc][k], Wl[k * 64 + o], acc);
            Y[row * 64 + o] = acc;
        }
    }
}

// ------------------------------------------------------- aggregation --------
// A[i,f] = H[i,f] * dinv[i]^2   (the self-loop message; also zero-inits A)
__global__ void selfloop_init_k(const float* __restrict__ H, const float* __restrict__ dinv,
                                float* __restrict__ A) {
    int idx = blockIdx.x * blockDim.x + threadIdx.x;
    if (idx < NN * EMB) {
        float di = dinv[idx >> 6];
        A[idx] = H[idx] * di * di;
    }
}

// one wave per edge: lane f does A[dst,f] += H[src,f] * dinv[src]*dinv[dst]
__global__ void scatter_k(const float* __restrict__ H, const float* __restrict__ dinv,
                          const int* __restrict__ src, const int* __restrict__ dst,
                          float* __restrict__ A, int n_edges) {
    int e = (blockIdx.x * blockDim.x + threadIdx.x) >> 6;
    int f = threadIdx.x & 63;
    if (e < n_edges) {
        int s = src[e], d = dst[e];
        float nrm = dinv[s] * dinv[d];
        atomicAdd(&A[d * 64 + f], H[s * 64 + f] * nrm);
    }
}

__global__ void bias_relu_k(float* __restrict__ A, const float* __restrict__ b) {
    int idx = blockIdx.x * blockDim.x + threadIdx.x;
    if (idx < NN * EMB) {
        int f = idx & 63;
        A[idx] = fmaxf(A[idx] + b[f], 0.0f);
    }
}

// ------------------------------------------------------------- head ---------
// out[i] = dot(H[i,:], W3) + b3 ; one wave per node, shuffle reduce
__global__ void head_k(const float* __restrict__ H, const float* __restrict__ W3,
                       const float* __restrict__ b3, float* __restrict__ out) {
    int node = (blockIdx.x * blockDim.x + threadIdx.x) >> 6;
    int f = threadIdx.x & 63;
    if (node < NN) {
        float v = H[node * 64 + f] * W3[f];
#pragma unroll
        for (int off = 32; off > 0; off >>= 1) v += __shfl_down(v, off, 64);
        if (f == 0) out[node] = v + b3[0];
    }
}

// ---------------------------------------------------------------------------
extern "C" void kernel_launch(void* const* d_in, const int* in_sizes, int n_in,
                              void* d_out, int out_size, void* d_ws, size_t ws_size,
                              hipStream_t stream) {
    const float* x   = (const float*)d_in[0];
    const int*   ei  = (const int*)d_in[1];
    const float* W1  = (const float*)d_in[2];
    const float* b1  = (const float*)d_in[3];
    const float* W2  = (const float*)d_in[4];
    const float* b2  = (const float*)d_in[5];
    const float* W3  = (const float*)d_in[6];
    const float* b3  = (const float*)d_in[7];
    float* out = (float*)d_out;

    const int E = in_sizes[1] / 2;
    const int* src = ei;
    const int* dst = ei + E;

    // workspace layout (floats): dinv[N] | bufA[N*64] | bufB[N*64]
    float* dinv = (float*)d_ws;
    float* bufA = dinv + NN;          // 100000 floats -> 16B aligned
    float* bufB = bufA + (size_t)NN * EMB;

    const int B = 256;
    const int gN   = (NN + B - 1) / B;
    const int gE   = (E + B - 1) / B;
    const int gNE  = (NN * EMB + B - 1) / B;
    const int gEw  = (E * 64 + B - 1) / B;    // wave per edge
    const int gNw  = (NN * 64 + B - 1) / B;   // wave per node

    // degrees -> dinv (in place)
    deg_init_k<<<gN, B, 0, stream>>>(dinv);
    deg_count_k<<<gE, B, 0, stream>>>(dst, dinv, E);
    dinv_k<<<gN, B, 0, stream>>>(dinv);

    // layer 1: h = x@W1 ; agg ; bias+relu
    gemm_rows_k<FIN><<<2048, B, 0, stream>>>(x, W1, bufA, NN);
    selfloop_init_k<<<gNE, B, 0, stream>>>(bufA, dinv, bufB);
    scatter_k<<<gEw, B, 0, stream>>>(bufA, dinv, src, dst, bufB, E);
    bias_relu_k<<<gNE, B, 0, stream>>>(bufB, b1);

    // layer 2: h = h1@W2 ; agg ; bias+relu
    gemm_rows_k<EMB><<<2048, B, 0, stream>>>(bufB, W2, bufA, NN);
    selfloop_init_k<<<gNE, B, 0, stream>>>(bufA, dinv, bufB);
    scatter_k<<<gEw, B, 0, stream>>>(bufA, dinv, src, dst, bufB, E);
    bias_relu_k<<<gNE, B, 0, stream>>>(bufB, b2);

    // head
    head_k<<<gNw, B, 0, stream>>>(bufB, W3, b3, out);
}

// Round 2
// 656.656 us; speedup vs baseline: 1.4480x; 1.4480x over previous
//
#include <hip/hip_runtime.h>
#include <hip/hip_bf16.h>

#define NN 100000     // nodes
#define FIN 128
#define EMB 64
#define SCAN_B 256

// ---------------------------------------------------------------- degree ----
__global__ void cnt_init_k(int* __restrict__ cnt) {
    int i = blockIdx.x * blockDim.x + threadIdx.x;
    if (i < NN) cnt[i] = 0;
}

__global__ void cnt_count_k(const int* __restrict__ dst, int* __restrict__ cnt, int n_edges) {
    int e = blockIdx.x * blockDim.x + threadIdx.x;
    if (e < n_edges) atomicAdd(&cnt[dst[e]], 1);
}

__global__ void dinv_k(const int* __restrict__ cnt, float* __restrict__ dinv) {
    int i = blockIdx.x * blockDim.x + threadIdx.x;
    if (i < NN) dinv[i] = rsqrtf((float)(cnt[i] + 1));   // +1 self-loop
}

// ---------------------------------------------------------------- scan ------
// exclusive prefix sum of cnt[N] -> rowptr[N+1], two-level Hillis-Steele
__global__ void scan1_k(const int* __restrict__ cnt, int* __restrict__ excl,
                        int* __restrict__ bsum, int n) {
    __shared__ int tmp[SCAN_B];
    int tid = threadIdx.x;
    int i = blockIdx.x * SCAN_B + tid;
    int v = (i < n) ? cnt[i] : 0;
    tmp[tid] = v; __syncthreads();
    for (int off = 1; off < SCAN_B; off <<= 1) {
        int t = (tid >= off) ? tmp[tid - off] : 0; __syncthreads();
        tmp[tid] += t; __syncthreads();
    }
    if (i < n) excl[i] = tmp[tid] - v;            // exclusive within block
    if (tid == SCAN_B - 1) bsum[blockIdx.x] = tmp[tid];
}

__global__ void scan2_k(int* __restrict__ bsum, int nb) {   // single block, nb<=512
    __shared__ int tmp[512];
    int tid = threadIdx.x;
    int v = (tid < nb) ? bsum[tid] : 0;
    tmp[tid] = v; __syncthreads();
    for (int off = 1; off < 512; off <<= 1) {
        int t = (tid >= off) ? tmp[tid - off] : 0; __syncthreads();
        tmp[tid] += t; __syncthreads();
    }
    if (tid < nb) bsum[tid] = tmp[tid] - v;       // exclusive
}

__global__ void scan3_k(const int* __restrict__ excl, const int* __restrict__ bsum,
                        int* __restrict__ rowptr, int* __restrict__ fill, int n, int n_edges) {
    int i = blockIdx.x * SCAN_B + threadIdx.x;
    if (i < n) {
        int r = excl[i] + bsum[blockIdx.x];
        rowptr[i] = r;
        fill[i] = r;
    }
    if (i == 0) rowptr[n] = n_edges;
}

// ---------------------------------------------------------------- fill ------
__global__ void fill_k(const int* __restrict__ src, const int* __restrict__ dst,
                       int* __restrict__ fill, int* __restrict__ csr, int n_edges) {
    int e = blockIdx.x * blockDim.x + threadIdx.x;
    if (e < n_edges) {
        int pos = atomicAdd(&fill[dst[e]], 1);
        csr[pos] = src[e];
    }
}

// ---------------------------------------------------------------- GEMM ------
// Y[row,o] = dinv[row] * sum_k X[row,k] * W[k,o].  256 thr = 4 rows x 64 outs.
template <int K>
__global__ void gemm_rows_k(const float* __restrict__ X, const float* __restrict__ W,
                            const float* __restrict__ dinv, float* __restrict__ Y,
                            int n_rows) {
    __shared__ float Wl[K * 64];
    __shared__ float Xl[4][K];
    for (int i = threadIdx.x; i < K * 64; i += blockDim.x) Wl[i] = W[i];

    const int o    = threadIdx.x & 63;
    const int rloc = threadIdx.x >> 6;

    for (int base = blockIdx.x * 4; base < n_rows; base += gridDim.x * 4) {
        __syncthreads();
        for (int i = threadIdx.x; i < 4 * K; i += blockDim.x) {
            int r = i / K, k = i - r * K;
            int row = base + r;
            Xl[r][k] = (row < n_rows) ? X[row * K + k] : 0.0f;
        }
        __syncthreads();
        int row = base + rloc;
        if (row < n_rows) {
            float acc = 0.0f;
#pragma unroll
            for (int k = 0; k < K; ++k)
                acc = fmaf(Xl[rloc][k], Wl[k * 64 + o], acc);
            Y[row * 64 + o] = acc * dinv[row];
        }
    }
}

// --------------------------------------------------------------- gather -----
// out[d,f] = relu( dinv[d] * (Hs[d,f] + sum_{s in N(d)} Hs[s,f]) + b[f] )
// where Hs already carries dinv[src]. One wave per node, lane = feature.
__global__ void gather_k(const float* __restrict__ Hs, const float* __restrict__ dinv,
                         const int* __restrict__ rowptr, const int* __restrict__ csr,
                         const float* __restrict__ bias, float* __restrict__ out) {
    int node = (blockIdx.x * blockDim.x + threadIdx.x) >> 6;
    int f = threadIdx.x & 63;
    if (node >= NN) return;
    int p0 = rowptr[node], p1 = rowptr[node + 1];
    float acc = Hs[node * 64 + f];                 // self-loop term
    for (int p = p0; p < p1; ++p) {
        int s = csr[p];
        acc += Hs[s * 64 + f];
    }
    out[node * 64 + f] = fmaxf(fmaf(acc, dinv[node], bias[f]), 0.0f);
}

// ------------------------------------------------------------- head ---------
__global__ void head_k(const float* __restrict__ H, const float* __restrict__ W3,
                       const float* __restrict__ b3, float* __restrict__ out) {
    int node = (blockIdx.x * blockDim.x + threadIdx.x) >> 6;
    int f = threadIdx.x & 63;
    if (node < NN) {
        float v = H[node * 64 + f] * W3[f];
#pragma unroll
        for (int off = 32; off > 0; off >>= 1) v += __shfl_down(v, off, 64);
        if (f == 0) out[node] = v + b3[0];
    }
}

// ---------------------------------------------------------------------------
extern "C" void kernel_launch(void* const* d_in, const int* in_sizes, int n_in,
                              void* d_out, int out_size, void* d_ws, size_t ws_size,
                              hipStream_t stream) {
    const float* x   = (const float*)d_in[0];
    const int*   ei  = (const int*)d_in[1];
    const float* W1  = (const float*)d_in[2];
    const float* b1  = (const float*)d_in[3];
    const float* W2  = (const float*)d_in[4];
    const float* b2  = (const float*)d_in[5];
    const float* W3  = (const float*)d_in[6];
    const float* b3  = (const float*)d_in[7];
    float* out = (float*)d_out;

    const int E = in_sizes[1] / 2;
    const int* src = ei;
    const int* dst = ei + E;

    // workspace layout (4B elems):
    // dinv[N] f32 | cnt[N] | excl[N] | rowptr[N+1] | fill[N] | bsum[512] |
    // csr[E] | bufA[N*64] f32 | bufB[N*64] f32
    float* dinv  = (float*)d_ws;
    int* cnt     = (int*)(dinv + NN);
    int* excl    = cnt + NN;
    int* rowptr  = excl + NN;
    int* fillp   = rowptr + NN + 1;
    int* bsum    = fillp + NN;
    int* csr     = bsum + 512;
    float* bufA  = (float*)(csr + E);
    float* bufB  = bufA + (size_t)NN * EMB;

    const int B = 256;
    const int gN  = (NN + B - 1) / B;          // per-node scalar
    const int gE  = (E + B - 1) / B;           // per-edge scalar
    const int gNw = (NN * 64 + B - 1) / B;     // wave per node
    const int nb  = gN;                        // scan blocks (391)

    // ---- CSR build (reused by both layers) ----
    cnt_init_k<<<gN, B, 0, stream>>>(cnt);
    cnt_count_k<<<gE, B, 0, stream>>>(dst, cnt, E);
    dinv_k<<<gN, B, 0, stream>>>(cnt, dinv);
    scan1_k<<<nb, SCAN_B, 0, stream>>>(cnt, excl, bsum, NN);
    scan2_k<<<1, 512, 0, stream>>>(bsum, nb);
    scan3_k<<<nb, SCAN_B, 0, stream>>>(excl, bsum, rowptr, fillp, NN, E);
    fill_k<<<gE, B, 0, stream>>>(src, dst, fillp, csr, E);

    // ---- layer 1 ----
    gemm_rows_k<FIN><<<2048, B, 0, stream>>>(x, W1, dinv, bufA, NN);
    gather_k<<<gNw, B, 0, stream>>>(bufA, dinv, rowptr, csr, b1, bufB);

    // ---- layer 2 ----
    gemm_rows_k<EMB><<<2048, B, 0, stream>>>(bufB, W2, dinv, bufA, NN);
    gather_k<<<gNw, B, 0, stream>>>(bufA, dinv, rowptr, csr, b2, bufB);

    // ---- head ----
    head_k<<<gNw, B, 0, stream>>>(bufB, W3, b3, out);
}

// Round 3
// 539.291 us; speedup vs baseline: 1.7631x; 1.2176x over previous
//
#include <hip/hip_runtime.h>
#include <hip/hip_bf16.h>
#include <hip/hip_fp16.h>

#define NN 100000     // nodes
#define FIN 128
#define EMB 64
#define SCAN_B 256

// ---------------------------------------------------------------- degree ----
__global__ void cnt_init_k(int* __restrict__ cnt) {
    int i = blockIdx.x * blockDim.x + threadIdx.x;
    if (i < NN) cnt[i] = 0;
}

__global__ void cnt_count_k(const int* __restrict__ dst, int* __restrict__ cnt, int n_edges) {
    int e = blockIdx.x * blockDim.x + threadIdx.x;
    if (e < n_edges) atomicAdd(&cnt[dst[e]], 1);
}

__global__ void dinv_k(const int* __restrict__ cnt, float* __restrict__ dinv) {
    int i = blockIdx.x * blockDim.x + threadIdx.x;
    if (i < NN) dinv[i] = rsqrtf((float)(cnt[i] + 1));   // +1 self-loop
}

// ---------------------------------------------------------------- scan ------
__global__ void scan1_k(const int* __restrict__ cnt, int* __restrict__ excl,
                        int* __restrict__ bsum, int n) {
    __shared__ int tmp[SCAN_B];
    int tid = threadIdx.x;
    int i = blockIdx.x * SCAN_B + tid;
    int v = (i < n) ? cnt[i] : 0;
    tmp[tid] = v; __syncthreads();
    for (int off = 1; off < SCAN_B; off <<= 1) {
        int t = (tid >= off) ? tmp[tid - off] : 0; __syncthreads();
        tmp[tid] += t; __syncthreads();
    }
    if (i < n) excl[i] = tmp[tid] - v;
    if (tid == SCAN_B - 1) bsum[blockIdx.x] = tmp[tid];
}

__global__ void scan2_k(int* __restrict__ bsum, int nb) {   // single block, nb<=512
    __shared__ int tmp[512];
    int tid = threadIdx.x;
    int v = (tid < nb) ? bsum[tid] : 0;
    tmp[tid] = v; __syncthreads();
    for (int off = 1; off < 512; off <<= 1) {
        int t = (tid >= off) ? tmp[tid - off] : 0; __syncthreads();
        tmp[tid] += t; __syncthreads();
    }
    if (tid < nb) bsum[tid] = tmp[tid] - v;
}

__global__ void scan3_k(const int* __restrict__ excl, const int* __restrict__ bsum,
                        int* __restrict__ rowptr, int* __restrict__ fill, int n, int n_edges) {
    int i = blockIdx.x * SCAN_B + threadIdx.x;
    if (i < n) {
        int r = excl[i] + bsum[blockIdx.x];
        rowptr[i] = r;
        fill[i] = r;
    }
    if (i == 0) rowptr[n] = n_edges;
}

__global__ void fill_k(const int* __restrict__ src, const int* __restrict__ dst,
                       int* __restrict__ fill, int* __restrict__ csr, int n_edges) {
    int e = blockIdx.x * blockDim.x + threadIdx.x;
    if (e < n_edges) {
        int pos = atomicAdd(&fill[dst[e]], 1);
        csr[pos] = src[e];
    }
}

// ---------------------------------------------------------------- GEMM ------
// Y[row,o] = fp16( dinv[row] * sum_k X[row,k] * W[k,o] ).  256 thr = 4 rows x 64 outs.
template <int K, typename TIN>
__global__ void gemm_rows_k(const TIN* __restrict__ X, const float* __restrict__ W,
                            const float* __restrict__ dinv, __half* __restrict__ Y,
                            int n_rows) {
    __shared__ float Wl[K * 64];
    __shared__ float Xl[4][K];
    for (int i = threadIdx.x; i < K * 64; i += blockDim.x) Wl[i] = W[i];

    const int o    = threadIdx.x & 63;
    const int rloc = threadIdx.x >> 6;

    for (int base = blockIdx.x * 4; base < n_rows; base += gridDim.x * 4) {
        __syncthreads();
        for (int i = threadIdx.x; i < 4 * K; i += blockDim.x) {
            int r = i / K, k = i - r * K;
            int row = base + r;
            Xl[r][k] = (row < n_rows) ? (float)X[row * K + k] : 0.0f;
        }
        __syncthreads();
        int row = base + rloc;
        if (row < n_rows) {
            float acc = 0.0f;
#pragma unroll
            for (int k = 0; k < K; ++k)
                acc = fmaf(Xl[rloc][k], Wl[k * 64 + o], acc);
            Y[row * 64 + o] = __float2half(acc * dinv[row]);
        }
    }
}

// --------------------------------------------------------------- gather -----
// One wave per node; 2 neighbors per iteration (each 32-lane half loads one
// 128B fp16 row as half2). fp32 accumulate; shfl_xor(32) combine.
// out[d] = fp16( relu( dinv[d]*(self + sum_neighbors) + b ) )
__global__ void gather_k(const __half2* __restrict__ H2, const float* __restrict__ dinv,
                         const int* __restrict__ rowptr, const int* __restrict__ csr,
                         const float* __restrict__ bias, __half2* __restrict__ out2) {
    int node = (blockIdx.x * blockDim.x + threadIdx.x) >> 6;
    if (node >= NN) return;
    const int lane = threadIdx.x & 63;
    const int half = lane >> 5;        // which neighbor of the pair
    const int fl   = lane & 31;        // feature pair index (features 2fl, 2fl+1)

    int p0 = rowptr[node], p1 = rowptr[node + 1];

    float2 acc = make_float2(0.0f, 0.0f);
    if (half == 0) {                   // self-loop term
        float2 s = __half22float2(H2[(size_t)node * 32 + fl]);
        acc.x += s.x; acc.y += s.y;
    }
    for (int p = p0; p < p1; p += 2) {
        int idx = p + half;
        if (idx < p1) {
            int s = csr[idx];
            float2 v = __half22float2(H2[(size_t)s * 32 + fl]);
            acc.x += v.x; acc.y += v.y;
        }
    }
    // combine the two halves
    acc.x += __shfl_xor(acc.x, 32, 64);
    acc.y += __shfl_xor(acc.y, 32, 64);

    if (half == 0) {
        float di = dinv[node];
        float2 b = ((const float2*)bias)[fl];
        float vx = fmaxf(fmaf(acc.x, di, b.x), 0.0f);
        float vy = fmaxf(fmaf(acc.y, di, b.y), 0.0f);
        out2[(size_t)node * 32 + fl] = __floats2half2_rn(vx, vy);
    }
}

// ------------------------------------------------------------- head ---------
// 2 nodes per wave: each 32-lane half dots one fp16 row with W3.
__global__ void head_k(const __half2* __restrict__ H2, const float* __restrict__ W3,
                       const float* __restrict__ b3, float* __restrict__ out) {
    int wave = (blockIdx.x * blockDim.x + threadIdx.x) >> 6;
    const int lane = threadIdx.x & 63;
    const int half = lane >> 5;
    const int fl   = lane & 31;
    int node = wave * 2 + half;
    if (node >= NN) return;
    float2 h = __half22float2(H2[(size_t)node * 32 + fl]);
    float2 w = ((const float2*)W3)[fl];
    float v = h.x * w.x + h.y * w.y;
#pragma unroll
    for (int off = 16; off > 0; off >>= 1) v += __shfl_xor(v, off, 64);
    if (fl == 0) out[node] = v + b3[0];
}

// ---------------------------------------------------------------------------
extern "C" void kernel_launch(void* const* d_in, const int* in_sizes, int n_in,
                              void* d_out, int out_size, void* d_ws, size_t ws_size,
                              hipStream_t stream) {
    const float* x   = (const float*)d_in[0];
    const int*   ei  = (const int*)d_in[1];
    const float* W1  = (const float*)d_in[2];
    const float* b1  = (const float*)d_in[3];
    const float* W2  = (const float*)d_in[4];
    const float* b2  = (const float*)d_in[5];
    const float* W3  = (const float*)d_in[6];
    const float* b3  = (const float*)d_in[7];
    float* out = (float*)d_out;

    const int E = in_sizes[1] / 2;
    const int* src = ei;
    const int* dst = ei + E;

    // workspace layout (4B units):
    // dinv[N] | cnt[N] | excl[N] | rowptr[N+1] | fill[N] | bsum[512] | csr[E]
    // | bufA (N*64 fp16 = N*32 u32) | bufB (same)
    float* dinv  = (float*)d_ws;
    int* cnt     = (int*)(dinv + NN);
    int* excl    = cnt + NN;
    int* rowptr  = excl + NN;
    int* fillp   = rowptr + NN + 1;
    int* bsum    = fillp + NN;
    int* csr     = bsum + 512;
    __half* bufA = (__half*)(csr + E);
    __half* bufB = bufA + (size_t)NN * EMB;

    const int B = 256;
    const int gN  = (NN + B - 1) / B;
    const int gE  = (E + B - 1) / B;
    const int gNw = (NN * 64 + B - 1) / B;     // one wave per node
    const int gNh = (NN + 7) / 8;              // head: 8 nodes per block
    const int nb  = gN;

    // ---- CSR build ----
    cnt_init_k<<<gN, B, 0, stream>>>(cnt);
    cnt_count_k<<<gE, B, 0, stream>>>(dst, cnt, E);
    dinv_k<<<gN, B, 0, stream>>>(cnt, dinv);
    scan1_k<<<nb, SCAN_B, 0, stream>>>(cnt, excl, bsum, NN);
    scan2_k<<<1, 512, 0, stream>>>(bsum, nb);
    scan3_k<<<nb, SCAN_B, 0, stream>>>(excl, bsum, rowptr, fillp, NN, E);
    fill_k<<<gE, B, 0, stream>>>(src, dst, fillp, csr, E);

    // ---- layer 1 ----
    gemm_rows_k<FIN, float><<<2048, B, 0, stream>>>(x, W1, dinv, bufA, NN);
    gather_k<<<gNw, B, 0, stream>>>((const __half2*)bufA, dinv, rowptr, csr, b1,
                                    (__half2*)bufB);

    // ---- layer 2 ----
    gemm_rows_k<EMB, __half><<<2048, B, 0, stream>>>(bufB, W2, dinv, bufA, NN);
    gather_k<<<gNw, B, 0, stream>>>((const __half2*)bufA, dinv, rowptr, csr, b2,
                                    (__half2*)bufB);

    // ---- head ----
    head_k<<<gNh, B, 0, stream>>>((const __half2*)bufB, W3, b3, out);
}

// Round 4
// 488.680 us; speedup vs baseline: 1.9457x; 1.1036x over previous
//
#include <hip/hip_runtime.h>
#include <hip/hip_bf16.h>
#include <hip/hip_fp16.h>

#define NN 100000     // nodes
#define FIN 128
#define EMB 64
#define SCAN_B 256
#define NGRP 8                  // dst-range groups, aligned to XCDs
#define GRP_SZ (NN / NGRP)      // 12500

// ---------------------------------------------------------------- degree ----
// cnt zeroed by hipMemsetAsync. Partitioned by dst-range so each range's cnt
// lines are touched by one XCD group only (blockIdx%8 -> XCD round-robin).
__global__ void cnt_count_k(const int* __restrict__ dst, int* __restrict__ cnt, int n_edges) {
    const int g   = blockIdx.x & (NGRP - 1);
    const int nb  = gridDim.x >> 3;
    const int bid = blockIdx.x >> 3;
    const int lo  = g * GRP_SZ, hi = lo + GRP_SZ;
    for (int base = bid * 256; base < n_edges; base += nb * 256) {
        int e = base + threadIdx.x;
        if (e < n_edges) {
            int d = dst[e];
            if (d >= lo && d < hi) atomicAdd(&cnt[d], 1);
        }
    }
}

// ---------------------------------------------------------------- scan ------
// also computes dinv (same cnt read)
__global__ void scan1_k(const int* __restrict__ cnt, int* __restrict__ excl,
                        int* __restrict__ bsum, float* __restrict__ dinv, int n) {
    __shared__ int tmp[SCAN_B];
    int tid = threadIdx.x;
    int i = blockIdx.x * SCAN_B + tid;
    int v = (i < n) ? cnt[i] : 0;
    if (i < n) dinv[i] = rsqrtf((float)(v + 1));   // +1 self-loop
    tmp[tid] = v; __syncthreads();
    for (int off = 1; off < SCAN_B; off <<= 1) {
        int t = (tid >= off) ? tmp[tid - off] : 0; __syncthreads();
        tmp[tid] += t; __syncthreads();
    }
    if (i < n) excl[i] = tmp[tid] - v;
    if (tid == SCAN_B - 1) bsum[blockIdx.x] = tmp[tid];
}

__global__ void scan2_k(int* __restrict__ bsum, int nb) {   // single block, nb<=512
    __shared__ int tmp[512];
    int tid = threadIdx.x;
    int v = (tid < nb) ? bsum[tid] : 0;
    tmp[tid] = v; __syncthreads();
    for (int off = 1; off < 512; off <<= 1) {
        int t = (tid >= off) ? tmp[tid - off] : 0; __syncthreads();
        tmp[tid] += t; __syncthreads();
    }
    if (tid < nb) bsum[tid] = tmp[tid] - v;
}

__global__ void scan3_k(const int* __restrict__ excl, const int* __restrict__ bsum,
                        int* __restrict__ rowptr, int* __restrict__ fill, int n, int n_edges) {
    int i = blockIdx.x * SCAN_B + threadIdx.x;
    if (i < n) {
        int r = excl[i] + bsum[blockIdx.x];
        rowptr[i] = r;
        fill[i] = r;
    }
    if (i == 0) rowptr[n] = n_edges;
}

// ---------------------------------------------------------------- fill ------
// XCD-partitioned: group g = blockIdx%8 handles dst in [g*12500,(g+1)*12500).
// Its csr slice (~800KB) is then written by one XCD only -> lines stay in that
// XCD's L2 until a single write-back (kills the 16x write amplification).
__global__ void fill_k(const int* __restrict__ src, const int* __restrict__ dst,
                       int* __restrict__ fillp, int* __restrict__ csr, int n_edges) {
    const int g   = blockIdx.x & (NGRP - 1);
    const int nb  = gridDim.x >> 3;
    const int bid = blockIdx.x >> 3;
    const int lo  = g * GRP_SZ, hi = lo + GRP_SZ;
    for (int base = bid * 256; base < n_edges; base += nb * 256) {
        int e = base + threadIdx.x;
        if (e < n_edges) {
            int d = dst[e];
            if (d >= lo && d < hi) {
                int pos = atomicAdd(&fillp[d], 1);
                csr[pos] = src[e];
            }
        }
    }
}

// ---------------------------------------------------------------- GEMM ------
// Y[row,o] = fp16( dinv[row] * sum_k X[row,k] * W[k,o] ).  256 thr = 4 rows x 64 outs.
template <int K, typename TIN>
__global__ void gemm_rows_k(const TIN* __restrict__ X, const float* __restrict__ W,
                            const float* __restrict__ dinv, __half* __restrict__ Y,
                            int n_rows) {
    __shared__ float Wl[K * 64];
    __shared__ float Xl[4][K];
    for (int i = threadIdx.x; i < K * 64; i += blockDim.x) Wl[i] = W[i];

    const int o    = threadIdx.x & 63;
    const int rloc = threadIdx.x >> 6;

    for (int base = blockIdx.x * 4; base < n_rows; base += gridDim.x * 4) {
        __syncthreads();
        for (int i = threadIdx.x; i < 4 * K; i += blockDim.x) {
            int r = i / K, k = i - r * K;
            int row = base + r;
            Xl[r][k] = (row < n_rows) ? (float)X[row * K + k] : 0.0f;
        }
        __syncthreads();
        int row = base + rloc;
        if (row < n_rows) {
            float acc = 0.0f;
#pragma unroll
            for (int k = 0; k < K; ++k)
                acc = fmaf(Xl[rloc][k], Wl[k * 64 + o], acc);
            Y[row * 64 + o] = __float2half(acc * dinv[row]);
        }
    }
}

// --------------------------------------------------------------- gather -----
__global__ void gather_k(const __half2* __restrict__ H2, const float* __restrict__ dinv,
                         const int* __restrict__ rowptr, const int* __restrict__ csr,
                         const float* __restrict__ bias, __half2* __restrict__ out2) {
    int node = (blockIdx.x * blockDim.x + threadIdx.x) >> 6;
    if (node >= NN) return;
    const int lane = threadIdx.x & 63;
    const int half = lane >> 5;        // which neighbor of the pair
    const int fl   = lane & 31;        // feature pair index

    int p0 = rowptr[node], p1 = rowptr[node + 1];

    float2 acc = make_float2(0.0f, 0.0f);
    if (half == 0) {                   // self-loop term
        float2 s = __half22float2(H2[(size_t)node * 32 + fl]);
        acc.x += s.x; acc.y += s.y;
    }
    for (int p = p0; p < p1; p += 2) {
        int idx = p + half;
        if (idx < p1) {
            int s = csr[idx];
            float2 v = __half22float2(H2[(size_t)s * 32 + fl]);
            acc.x += v.x; acc.y += v.y;
        }
    }
    acc.x += __shfl_xor(acc.x, 32, 64);
    acc.y += __shfl_xor(acc.y, 32, 64);

    if (half == 0) {
        float di = dinv[node];
        float2 b = ((const float2*)bias)[fl];
        float vx = fmaxf(fmaf(acc.x, di, b.x), 0.0f);
        float vy = fmaxf(fmaf(acc.y, di, b.y), 0.0f);
        out2[(size_t)node * 32 + fl] = __floats2half2_rn(vx, vy);
    }
}

// ------------------------------------------------------------- head ---------
__global__ void head_k(const __half2* __restrict__ H2, const float* __restrict__ W3,
                       const float* __restrict__ b3, float* __restrict__ out) {
    int wave = (blockIdx.x * blockDim.x + threadIdx.x) >> 6;
    const int lane = threadIdx.x & 63;
    const int half = lane >> 5;
    const int fl   = lane & 31;
    int node = wave * 2 + half;
    if (node >= NN) return;
    float2 h = __half22float2(H2[(size_t)node * 32 + fl]);
    float2 w = ((const float2*)W3)[fl];
    float v = h.x * w.x + h.y * w.y;
#pragma unroll
    for (int off = 16; off > 0; off >>= 1) v += __shfl_xor(v, off, 64);
    if (fl == 0) out[node] = v + b3[0];
}

// ---------------------------------------------------------------------------
extern "C" void kernel_launch(void* const* d_in, const int* in_sizes, int n_in,
                              void* d_out, int out_size, void* d_ws, size_t ws_size,
                              hipStream_t stream) {
    const float* x   = (const float*)d_in[0];
    const int*   ei  = (const int*)d_in[1];
    const float* W1  = (const float*)d_in[2];
    const float* b1  = (const float*)d_in[3];
    const float* W2  = (const float*)d_in[4];
    const float* b2  = (const float*)d_in[5];
    const float* W3  = (const float*)d_in[6];
    const float* b3  = (const float*)d_in[7];
    float* out = (float*)d_out;

    const int E = in_sizes[1] / 2;
    const int* src = ei;
    const int* dst = ei + E;

    // workspace layout (4B units):
    // dinv[N] | cnt[N] | excl[N] | rowptr[N+1] | fill[N] | bsum[512] | csr[E]
    // | bufA (N*64 fp16) | bufB (same)
    float* dinv  = (float*)d_ws;
    int* cnt     = (int*)(dinv + NN);
    int* excl    = cnt + NN;
    int* rowptr  = excl + NN;
    int* fillp   = rowptr + NN + 1;
    int* bsum    = fillp + NN;
    int* csr     = bsum + 512;
    __half* bufA = (__half*)(csr + E);
    __half* bufB = bufA + (size_t)NN * EMB;

    const int B = 256;
    const int gN  = (NN + B - 1) / B;
    const int gNw = (NN * 64 + B - 1) / B;     // one wave per node
    const int gNh = (NN + 7) / 8;              // head: 8 nodes per block
    const int nb  = gN;
    const int gFill = 1024;                    // 128 blocks per XCD group

    // ---- CSR build ----
    hipMemsetAsync(cnt, 0, NN * sizeof(int), stream);
    cnt_count_k<<<gFill, B, 0, stream>>>(dst, cnt, E);
    scan1_k<<<nb, SCAN_B, 0, stream>>>(cnt, excl, bsum, dinv, NN);
    scan2_k<<<1, 512, 0, stream>>>(bsum, nb);
    scan3_k<<<nb, SCAN_B, 0, stream>>>(excl, bsum, rowptr, fillp, NN, E);
    fill_k<<<gFill, B, 0, stream>>>(src, dst, fillp, csr, E);

    // ---- layer 1 ----
    gemm_rows_k<FIN, float><<<2048, B, 0, stream>>>(x, W1, dinv, bufA, NN);
    gather_k<<<gNw, B, 0, stream>>>((const __half2*)bufA, dinv, rowptr, csr, b1,
                                    (__half2*)bufB);

    // ---- layer 2 ----
    gemm_rows_k<EMB, __half><<<2048, B, 0, stream>>>(bufB, W2, dinv, bufA, NN);
    gather_k<<<gNw, B, 0, stream>>>((const __half2*)bufA, dinv, rowptr, csr, b2,
                                    (__half2*)bufB);

    // ---- head ----
    head_k<<<gNh, B, 0, stream>>>((const __half2*)bufB, W3, b3, out);
}

// Round 5
// 383.162 us; speedup vs baseline: 2.4815x; 1.2754x over previous
//
#include <hip/hip_runtime.h>
#include <hip/hip_bf16.h>
#include <hip/hip_fp16.h>

#define NN 100000     // nodes
#define FIN 128
#define EMB 64
#define SCAN_B 256
#define NGRP 8                  // dst-range groups, aligned to XCDs
#define GRP_SZ (NN / NGRP)      // 12500

using half8 = __attribute__((ext_vector_type(8))) _Float16;
using f32x4 = __attribute__((ext_vector_type(4))) float;

// ---------------------------------------------------------------- degree ----
__global__ void cnt_count_k(const int* __restrict__ dst, int* __restrict__ cnt, int n_edges) {
    const int g   = blockIdx.x & (NGRP - 1);
    const int nb  = gridDim.x >> 3;
    const int bid = blockIdx.x >> 3;
    const int lo  = g * GRP_SZ, hi = lo + GRP_SZ;
    for (int base = bid * 256; base < n_edges; base += nb * 256) {
        int e = base + threadIdx.x;
        if (e < n_edges) {
            int d = dst[e];
            if (d >= lo && d < hi) atomicAdd(&cnt[d], 1);
        }
    }
}

// ---------------------------------------------------------------- scan ------
__global__ void scan1_k(const int* __restrict__ cnt, int* __restrict__ excl,
                        int* __restrict__ bsum, float* __restrict__ dinv, int n) {
    __shared__ int tmp[SCAN_B];
    int tid = threadIdx.x;
    int i = blockIdx.x * SCAN_B + tid;
    int v = (i < n) ? cnt[i] : 0;
    if (i < n) dinv[i] = rsqrtf((float)(v + 1));   // +1 self-loop
    tmp[tid] = v; __syncthreads();
    for (int off = 1; off < SCAN_B; off <<= 1) {
        int t = (tid >= off) ? tmp[tid - off] : 0; __syncthreads();
        tmp[tid] += t; __syncthreads();
    }
    if (i < n) excl[i] = tmp[tid] - v;
    if (tid == SCAN_B - 1) bsum[blockIdx.x] = tmp[tid];
}

__global__ void scan2_k(int* __restrict__ bsum, int nb) {   // single block, nb<=512
    __shared__ int tmp[512];
    int tid = threadIdx.x;
    int v = (tid < nb) ? bsum[tid] : 0;
    tmp[tid] = v; __syncthreads();
    for (int off = 1; off < 512; off <<= 1) {
        int t = (tid >= off) ? tmp[tid - off] : 0; __syncthreads();
        tmp[tid] += t; __syncthreads();
    }
    if (tid < nb) bsum[tid] = tmp[tid] - v;
}

__global__ void scan3_k(const int* __restrict__ excl, const int* __restrict__ bsum,
                        int* __restrict__ rowptr, int* __restrict__ fill, int n, int n_edges) {
    int i = blockIdx.x * SCAN_B + threadIdx.x;
    if (i < n) {
        int r = excl[i] + bsum[blockIdx.x];
        rowptr[i] = r;
        fill[i] = r;
    }
    if (i == 0) rowptr[n] = n_edges;
}

// ---------------------------------------------------------------- fill ------
__global__ void fill_k(const int* __restrict__ src, const int* __restrict__ dst,
                       int* __restrict__ fillp, int* __restrict__ csr, int n_edges) {
    const int g   = blockIdx.x & (NGRP - 1);
    const int nb  = gridDim.x >> 3;
    const int bid = blockIdx.x >> 3;
    const int lo  = g * GRP_SZ, hi = lo + GRP_SZ;
    for (int base = bid * 256; base < n_edges; base += nb * 256) {
        int e = base + threadIdx.x;
        if (e < n_edges) {
            int d = dst[e];
            if (d >= lo && d < hi) {
                int pos = atomicAdd(&fillp[d], 1);
                csr[pos] = src[e];
            }
        }
    }
}

// ------------------------------------------------------------ MFMA GEMM ----
// Y[row,o] = fp16( dinv[row] * sum_k X[row,k] * W[k,o] ), N=64 outputs.
// Block = 4 waves; each wave owns one 16-row x 64-col tile per iteration.
// W (K x 64) -> fp16 LDS -> B-fragments hoisted to registers, reused for all
// row tiles. A-fragments loaded directly from global.
// Fragment layout (gfx950 16x16x32): A row = lane&15, k = (lane>>4)*8 + j;
// B col = lane&15, same k; D col = lane&15, row = (lane>>4)*4 + reg.
template <int K, typename TIN>
__global__ void gemm_mfma_k(const TIN* __restrict__ X, const float* __restrict__ W,
                            const float* __restrict__ dinv, __half* __restrict__ Y,
                            int n_tiles) {
    __shared__ _Float16 Wl[K * 64];
    for (int i = threadIdx.x; i < K * 64; i += 256) Wl[i] = (_Float16)W[i];
    __syncthreads();

    const int lane = threadIdx.x & 63;
    const int wid  = threadIdx.x >> 6;   // 0..3
    const int col0 = lane & 15;
    const int kg   = lane >> 4;          // 0..3

    // hoist B fragments: [4 col-tiles][K/32 k-steps]
    half8 bf[4][K / 32];
#pragma unroll
    for (int t = 0; t < 4; ++t)
#pragma unroll
        for (int s = 0; s < K / 32; ++s) {
            half8 b;
#pragma unroll
            for (int j = 0; j < 8; ++j) {
                int k = s * 32 + kg * 8 + j;
                b[j] = Wl[k * 64 + t * 16 + col0];
            }
            bf[t][s] = b;
        }

    const int nwaves = gridDim.x * 4;
    for (int tile = blockIdx.x * 4 + wid; tile < n_tiles; tile += nwaves) {
        const int row0 = tile * 16;
        const int arow = row0 + col0;

        half8 af[K / 32];
#pragma unroll
        for (int s = 0; s < K / 32; ++s) {
            if constexpr (sizeof(TIN) == 4) {
                const float* p = (const float*)X + (size_t)arow * K + s * 32 + kg * 8;
                f32x4 v0 = *(const f32x4*)p;
                f32x4 v1 = *(const f32x4*)(p + 4);
                half8 a;
#pragma unroll
                for (int j = 0; j < 4; ++j) { a[j] = (_Float16)v0[j]; a[4 + j] = (_Float16)v1[j]; }
                af[s] = a;
            } else {
                const __half* p = (const __half*)X + (size_t)arow * K + s * 32 + kg * 8;
                af[s] = *(const half8*)p;
            }
        }

        f32x4 acc[4];
#pragma unroll
        for (int t = 0; t < 4; ++t) acc[t] = (f32x4){0.f, 0.f, 0.f, 0.f};
#pragma unroll
        for (int s = 0; s < K / 32; ++s)
#pragma unroll
            for (int t = 0; t < 4; ++t)
                acc[t] = __builtin_amdgcn_mfma_f32_16x16x32_f16(af[s], bf[t][s], acc[t], 0, 0, 0);

        float dv[4];
#pragma unroll
        for (int r = 0; r < 4; ++r) dv[r] = dinv[row0 + kg * 4 + r];
#pragma unroll
        for (int t = 0; t < 4; ++t)
#pragma unroll
            for (int r = 0; r < 4; ++r) {
                int row = row0 + kg * 4 + r;
                Y[(size_t)row * 64 + t * 16 + col0] = __float2half(acc[t][r] * dv[r]);
            }
    }
}

// --------------------------------------------------------------- gather -----
__global__ void gather_k(const __half2* __restrict__ H2, const float* __restrict__ dinv,
                         const int* __restrict__ rowptr, const int* __restrict__ csr,
                         const float* __restrict__ bias, __half2* __restrict__ out2) {
    int node = (blockIdx.x * blockDim.x + threadIdx.x) >> 6;
    if (node >= NN) return;
    const int lane = threadIdx.x & 63;
    const int half = lane >> 5;        // which neighbor of the pair
    const int fl   = lane & 31;        // feature pair index

    int p0 = rowptr[node], p1 = rowptr[node + 1];

    float2 acc = make_float2(0.0f, 0.0f);
    if (half == 0) {                   // self-loop term
        float2 s = __half22float2(H2[(size_t)node * 32 + fl]);
        acc.x += s.x; acc.y += s.y;
    }
    for (int p = p0; p < p1; p += 2) {
        int idx = p + half;
        if (idx < p1) {
            int s = csr[idx];
            float2 v = __half22float2(H2[(size_t)s * 32 + fl]);
            acc.x += v.x; acc.y += v.y;
        }
    }
    acc.x += __shfl_xor(acc.x, 32, 64);
    acc.y += __shfl_xor(acc.y, 32, 64);

    if (half == 0) {
        float di = dinv[node];
        float2 b = ((const float2*)bias)[fl];
        float vx = fmaxf(fmaf(acc.x, di, b.x), 0.0f);
        float vy = fmaxf(fmaf(acc.y, di, b.y), 0.0f);
        out2[(size_t)node * 32 + fl] = __floats2half2_rn(vx, vy);
    }
}

// ------------------------------------------------------------- head ---------
__global__ void head_k(const __half2* __restrict__ H2, const float* __restrict__ W3,
                       const float* __restrict__ b3, float* __restrict__ out) {
    int wave = (blockIdx.x * blockDim.x + threadIdx.x) >> 6;
    const int lane = threadIdx.x & 63;
    const int half = lane >> 5;
    const int fl   = lane & 31;
    int node = wave * 2 + half;
    if (node >= NN) return;
    float2 h = __half22float2(H2[(size_t)node * 32 + fl]);
    float2 w = ((const float2*)W3)[fl];
    float v = h.x * w.x + h.y * w.y;
#pragma unroll
    for (int off = 16; off > 0; off >>= 1) v += __shfl_xor(v, off, 64);
    if (fl == 0) out[node] = v + b3[0];
}

// ---------------------------------------------------------------------------
extern "C" void kernel_launch(void* const* d_in, const int* in_sizes, int n_in,
                              void* d_out, int out_size, void* d_ws, size_t ws_size,
                              hipStream_t stream) {
    const float* x   = (const float*)d_in[0];
    const int*   ei  = (const int*)d_in[1];
    const float* W1  = (const float*)d_in[2];
    const float* b1  = (const float*)d_in[3];
    const float* W2  = (const float*)d_in[4];
    const float* b2  = (const float*)d_in[5];
    const float* W3  = (const float*)d_in[6];
    const float* b3  = (const float*)d_in[7];
    float* out = (float*)d_out;

    const int E = in_sizes[1] / 2;
    const int* src = ei;
    const int* dst = ei + E;

    // workspace layout (4B units):
    // dinv[N] | cnt[N] | excl[N] | rowptr[N+1] | fill[N] | bsum[512] | csr[E]
    // | bufA (N*64 fp16) | bufB (same)
    float* dinv  = (float*)d_ws;
    int* cnt     = (int*)(dinv + NN);
    int* excl    = cnt + NN;
    int* rowptr  = excl + NN;
    int* fillp   = rowptr + NN + 1;
    int* bsum    = fillp + NN;
    int* csr     = bsum + 512;
    __half* bufA = (__half*)(csr + E);
    __half* bufB = bufA + (size_t)NN * EMB;

    const int B = 256;
    const int gNw = (NN * 64 + B - 1) / B;     // one wave per node
    const int gNh = (NN + 7) / 8;              // head: 8 nodes per block
    const int nb  = (NN + SCAN_B - 1) / SCAN_B;
    const int gFill = 1024;                    // 128 blocks per XCD group
    const int nTiles = NN / 16;                // 6250 exact
    const int gGemm = (nTiles + 3) / 4;        // 4 waves per block, single pass

    // ---- CSR build ----
    hipMemsetAsync(cnt, 0, NN * sizeof(int), stream);
    cnt_count_k<<<gFill, B, 0, stream>>>(dst, cnt, E);
    scan1_k<<<nb, SCAN_B, 0, stream>>>(cnt, excl, bsum, dinv, NN);
    scan2_k<<<1, 512, 0, stream>>>(bsum, nb);
    scan3_k<<<nb, SCAN_B, 0, stream>>>(excl, bsum, rowptr, fillp, NN, E);
    fill_k<<<gFill, B, 0, stream>>>(src, dst, fillp, csr, E);

    // ---- layer 1 ----
    gemm_mfma_k<FIN, float><<<gGemm, B, 0, stream>>>(x, W1, dinv, bufA, nTiles);
    gather_k<<<gNw, B, 0, stream>>>((const __half2*)bufA, dinv, rowptr, csr, b1,
                                    (__half2*)bufB);

    // ---- layer 2 ----
    gemm_mfma_k<EMB, __half><<<gGemm, B, 0, stream>>>(bufB, W2, dinv, bufA, nTiles);
    gather_k<<<gNw, B, 0, stream>>>((const __half2*)bufA, dinv, rowptr, csr, b2,
                                    (__half2*)bufB);

    // ---- head ----
    head_k<<<gNh, B, 0, stream>>>((const __half2*)bufB, W3, b3, out);
}

// Round 7
// 302.007 us; speedup vs baseline: 3.1484x; 1.2687x over previous
//
#include <hip/hip_runtime.h>
#include <hip/hip_bf16.h>
#include <hip/hip_fp16.h>

#define NN 100000     // nodes
#define FIN 128
#define EMB 64
#define SCAN_B 256
#define NGRP 8                  // dst-range groups, aligned to XCDs
#define GRP_SZ (NN / NGRP)      // 12500

using half8 = __attribute__((ext_vector_type(8))) _Float16;
using f32x4 = __attribute__((ext_vector_type(4))) float;

// ---------------------------------------------------------------- degree ----
__global__ void cnt_count_k(const int* __restrict__ dst, int* __restrict__ cnt, int n_edges) {
    const int g   = blockIdx.x & (NGRP - 1);
    const int nb  = gridDim.x >> 3;
    const int bid = blockIdx.x >> 3;
    const int lo  = g * GRP_SZ, hi = lo + GRP_SZ;
    for (int base = bid * 256; base < n_edges; base += nb * 256) {
        int e = base + threadIdx.x;
        if (e < n_edges) {
            int d = dst[e];
            if (d >= lo && d < hi) atomicAdd(&cnt[d], 1);
        }
    }
}

// ---------------------------------------------------------------- scan ------
__global__ void scan1_k(const int* __restrict__ cnt, int* __restrict__ excl,
                        int* __restrict__ bsum, float* __restrict__ dinv, int n) {
    __shared__ int tmp[SCAN_B];
    int tid = threadIdx.x;
    int i = blockIdx.x * SCAN_B + tid;
    int v = (i < n) ? cnt[i] : 0;
    if (i < n) dinv[i] = rsqrtf((float)(v + 1));   // +1 self-loop
    tmp[tid] = v; __syncthreads();
    for (int off = 1; off < SCAN_B; off <<= 1) {
        int t = (tid >= off) ? tmp[tid - off] : 0; __syncthreads();
        tmp[tid] += t; __syncthreads();
    }
    if (i < n) excl[i] = tmp[tid] - v;
    if (tid == SCAN_B - 1) bsum[blockIdx.x] = tmp[tid];
}

__global__ void scan2_k(int* __restrict__ bsum, int nb) {   // single block, nb<=512
    __shared__ int tmp[512];
    int tid = threadIdx.x;
    int v = (tid < nb) ? bsum[tid] : 0;
    tmp[tid] = v; __syncthreads();
    for (int off = 1; off < 512; off <<= 1) {
        int t = (tid >= off) ? tmp[tid - off] : 0; __syncthreads();
        tmp[tid] += t; __syncthreads();
    }
    if (tid < nb) bsum[tid] = tmp[tid] - v;
}

__global__ void scan3_k(const int* __restrict__ excl, const int* __restrict__ bsum,
                        int* __restrict__ rowptr, int* __restrict__ fill, int n, int n_edges) {
    int i = blockIdx.x * SCAN_B + threadIdx.x;
    if (i < n) {
        int r = excl[i] + bsum[blockIdx.x];
        rowptr[i] = r;
        fill[i] = r;
    }
    if (i == 0) rowptr[n] = n_edges;
}

// ---------------------------------------------------------------- fill ------
__global__ void fill_k(const int* __restrict__ src, const int* __restrict__ dst,
                       int* __restrict__ fillp, int* __restrict__ csr, int n_edges) {
    const int g   = blockIdx.x & (NGRP - 1);
    const int nb  = gridDim.x >> 3;
    const int bid = blockIdx.x >> 3;
    const int lo  = g * GRP_SZ, hi = lo + GRP_SZ;
    for (int base = bid * 256; base < n_edges; base += nb * 256) {
        int e = base + threadIdx.x;
        if (e < n_edges) {
            int d = dst[e];
            if (d >= lo && d < hi) {
                int pos = atomicAdd(&fillp[d], 1);
                csr[pos] = src[e];
            }
        }
    }
}

// ------------------------------------------------------------ MFMA GEMM ----
template <int K, typename TIN>
__global__ void gemm_mfma_k(const TIN* __restrict__ X, const float* __restrict__ W,
                            const float* __restrict__ dinv, __half* __restrict__ Y,
                            int n_tiles) {
    __shared__ _Float16 Wl[K * 64];
    for (int i = threadIdx.x; i < K * 64; i += 256) Wl[i] = (_Float16)W[i];
    __syncthreads();

    const int lane = threadIdx.x & 63;
    const int wid  = threadIdx.x >> 6;   // 0..3
    const int col0 = lane & 15;
    const int kg   = lane >> 4;          // 0..3

    half8 bf[4][K / 32];
#pragma unroll
    for (int t = 0; t < 4; ++t)
#pragma unroll
        for (int s = 0; s < K / 32; ++s) {
            half8 b;
#pragma unroll
            for (int j = 0; j < 8; ++j) {
                int k = s * 32 + kg * 8 + j;
                b[j] = Wl[k * 64 + t * 16 + col0];
            }
            bf[t][s] = b;
        }

    const int nwaves = gridDim.x * 4;
    for (int tile = blockIdx.x * 4 + wid; tile < n_tiles; tile += nwaves) {
        const int row0 = tile * 16;
        const int arow = row0 + col0;

        half8 af[K / 32];
#pragma unroll
        for (int s = 0; s < K / 32; ++s) {
            if constexpr (sizeof(TIN) == 4) {
                const float* p = (const float*)X + (size_t)arow * K + s * 32 + kg * 8;
                f32x4 v0 = *(const f32x4*)p;
                f32x4 v1 = *(const f32x4*)(p + 4);
                half8 a;
#pragma unroll
                for (int j = 0; j < 4; ++j) { a[j] = (_Float16)v0[j]; a[4 + j] = (_Float16)v1[j]; }
                af[s] = a;
            } else {
                const __half* p = (const __half*)X + (size_t)arow * K + s * 32 + kg * 8;
                af[s] = *(const half8*)p;
            }
        }

        f32x4 acc[4];
#pragma unroll
        for (int t = 0; t < 4; ++t) acc[t] = (f32x4){0.f, 0.f, 0.f, 0.f};
#pragma unroll
        for (int s = 0; s < K / 32; ++s)
#pragma unroll
            for (int t = 0; t < 4; ++t)
                acc[t] = __builtin_amdgcn_mfma_f32_16x16x32_f16(af[s], bf[t][s], acc[t], 0, 0, 0);

        float dv[4];
#pragma unroll
        for (int r = 0; r < 4; ++r) dv[r] = dinv[row0 + kg * 4 + r];
#pragma unroll
        for (int t = 0; t < 4; ++t)
#pragma unroll
            for (int r = 0; r < 4; ++r) {
                int row = row0 + kg * 4 + r;
                Y[(size_t)row * 64 + t * 16 + col0] = __float2half(acc[t][r] * dv[r]);
            }
    }
}

// --------------------------------------------------------------- gather -----
// One wave per node; 4 x 16-lane groups each load one 128B fp16 row (8B/lane).
// Per 64-neighbor chunk: ONE coalesced csr read, indices distributed by shfl.
// Shfl trip count is WAVE-UNIFORM (jmax = ceil(m/4)) so every shfl executes
// with all 64 source lanes active; only the load/accumulate is predicated.
__global__ void gather_k(const float2* __restrict__ H4, const float* __restrict__ dinv,
                         const int* __restrict__ rowptr, const int* __restrict__ csr,
                         const float* __restrict__ bias, uint2* __restrict__ out4) {
    int node = (blockIdx.x * blockDim.x + threadIdx.x) >> 6;
    if (node >= NN) return;
    const int lane = threadIdx.x & 63;
    const int q  = lane >> 4;      // quarter 0..3 (row group)
    const int fl = lane & 15;      // feature 4-pack (features 4fl..4fl+3)

    const int p0 = rowptr[node], p1 = rowptr[node + 1];

    float4 acc = make_float4(0.f, 0.f, 0.f, 0.f);
    if (q == 0) {                  // self-loop row
        float2 v = H4[(size_t)node * 16 + fl];
        const __half2* h = (const __half2*)&v;
        float2 a = __half22float2(h[0]), b = __half22float2(h[1]);
        acc.x += a.x; acc.y += a.y; acc.z += b.x; acc.w += b.y;
    }

    for (int base = p0; base < p1; base += 64) {
        int pos = base + lane;
        int cidx = (pos < p1) ? csr[pos] : 0;       // one coalesced read / chunk
        int m = p1 - base; if (m > 64) m = 64;
        int jmax = (m + 3) >> 2;                    // wave-uniform trip count
#pragma unroll 4
        for (int j = 0; j < jmax; ++j) {
            int nb = (j << 2) + q;                  // this quarter's neighbor slot
            int s = __shfl(cidx, nb, 64);           // all 64 lanes execute
            if (nb < m) {
                float2 v = H4[(size_t)s * 16 + fl];
                const __half2* h = (const __half2*)&v;
                float2 a = __half22float2(h[0]), b = __half22float2(h[1]);
                acc.x += a.x; acc.y += a.y; acc.z += b.x; acc.w += b.y;
            }
        }
    }

    // combine the 4 quarters
    acc.x += __shfl_xor(acc.x, 16, 64); acc.y += __shfl_xor(acc.y, 16, 64);
    acc.z += __shfl_xor(acc.z, 16, 64); acc.w += __shfl_xor(acc.w, 16, 64);
    acc.x += __shfl_xor(acc.x, 32, 64); acc.y += __shfl_xor(acc.y, 32, 64);
    acc.z += __shfl_xor(acc.z, 32, 64); acc.w += __shfl_xor(acc.w, 32, 64);

    if (q == 0) {
        float di = dinv[node];
        float4 b = ((const float4*)bias)[fl];
        float vx = fmaxf(fmaf(acc.x, di, b.x), 0.f);
        float vy = fmaxf(fmaf(acc.y, di, b.y), 0.f);
        float vz = fmaxf(fmaf(acc.z, di, b.z), 0.f);
        float vw = fmaxf(fmaf(acc.w, di, b.w), 0.f);
        __half2 lo = __floats2half2_rn(vx, vy), hi = __floats2half2_rn(vz, vw);
        uint2 o; o.x = *(const uint*)&lo; o.y = *(const uint*)&hi;
        out4[(size_t)node * 16 + fl] = o;
    }
}

// ------------------------------------------------------------- head ---------
__global__ void head_k(const __half2* __restrict__ H2, const float* __restrict__ W3,
                       const float* __restrict__ b3, float* __restrict__ out) {
    int wave = (blockIdx.x * blockDim.x + threadIdx.x) >> 6;
    const int lane = threadIdx.x & 63;
    const int half = lane >> 5;
    const int fl   = lane & 31;
    int node = wave * 2 + half;
    if (node >= NN) return;
    float2 h = __half22float2(H2[(size_t)node * 32 + fl]);
    float2 w = ((const float2*)W3)[fl];
    float v = h.x * w.x + h.y * w.y;
#pragma unroll
    for (int off = 16; off > 0; off >>= 1) v += __shfl_xor(v, off, 64);
    if (fl == 0) out[node] = v + b3[0];
}

// ---------------------------------------------------------------------------
extern "C" void kernel_launch(void* const* d_in, const int* in_sizes, int n_in,
                              void* d_out, int out_size, void* d_ws, size_t ws_size,
                              hipStream_t stream) {
    const float* x   = (const float*)d_in[0];
    const int*   ei  = (const int*)d_in[1];
    const float* W1  = (const float*)d_in[2];
    const float* b1  = (const float*)d_in[3];
    const float* W2  = (const float*)d_in[4];
    const float* b2  = (const float*)d_in[5];
    const float* W3  = (const float*)d_in[6];
    const float* b3  = (const float*)d_in[7];
    float* out = (float*)d_out;

    const int E = in_sizes[1] / 2;
    const int* src = ei;
    const int* dst = ei + E;

    // workspace layout (4B units):
    // dinv[N] | cnt[N] | excl[N] | rowptr[N+1] | fill[N] | bsum[512] | csr[E]
    // | bufA (N*64 fp16) | bufB (same)
    float* dinv  = (float*)d_ws;
    int* cnt     = (int*)(dinv + NN);
    int* excl    = cnt + NN;
    int* rowptr  = excl + NN;
    int* fillp   = rowptr + NN + 1;
    int* bsum    = fillp + NN;
    int* csr     = bsum + 512;
    __half* bufA = (__half*)(csr + E);
    __half* bufB = bufA + (size_t)NN * EMB;

    const int B = 256;
    const int gNw = (NN * 64 + B - 1) / B;     // one wave per node
    const int gNh = (NN + 7) / 8;              // head: 8 nodes per block
    const int nb  = (NN + SCAN_B - 1) / SCAN_B;
    const int gFill = 1024;                    // 128 blocks per XCD group
    const int nTiles = NN / 16;                // 6250 exact
    const int gGemm = (nTiles + 3) / 4;        // 4 waves per block

    // ---- CSR build ----
    hipMemsetAsync(cnt, 0, NN * sizeof(int), stream);
    cnt_count_k<<<gFill, B, 0, stream>>>(dst, cnt, E);
    scan1_k<<<nb, SCAN_B, 0, stream>>>(cnt, excl, bsum, dinv, NN);
    scan2_k<<<1, 512, 0, stream>>>(bsum, nb);
    scan3_k<<<nb, SCAN_B, 0, stream>>>(excl, bsum, rowptr, fillp, NN, E);
    fill_k<<<gFill, B, 0, stream>>>(src, dst, fillp, csr, E);

    // ---- layer 1 ----
    gemm_mfma_k<FIN, float><<<gGemm, B, 0, stream>>>(x, W1, dinv, bufA, nTiles);
    gather_k<<<gNw, B, 0, stream>>>((const float2*)bufA, dinv, rowptr, csr, b1,
                                    (uint2*)bufB);

    // ---- layer 2 ----
    gemm_mfma_k<EMB, __half><<<gGemm, B, 0, stream>>>(bufB, W2, dinv, bufA, nTiles);
    gather_k<<<gNw, B, 0, stream>>>((const float2*)bufA, dinv, rowptr, csr, b2,
                                    (uint2*)bufB);

    // ---- head ----
    head_k<<<gNh, B, 0, stream>>>((const __half2*)bufB, W3, b3, out);
}